// Round 6
// baseline (334.092 us; speedup 1.0000x reference)
//
#include <hip/hip_runtime.h>

// B=4096, ID=2048, OD=1024. 4-level pyramidal LSTM, f32 I/O.
// GEMM: 256x256 tile, 2-phase/K-tile pipeline: 2 barriers + 1 counted vmcnt(4)
// per K-tile, issue-order-proven staging slots (no latency races), T2 LDS
// swizzle, T5 setprio, T1 XCD swizzle. LSTM cell fused in epilogue via
// gate-interleaved weight permutation (W row p <- q*H+o, p=64*(o>>4)+16*q+(o&15)).

typedef __bf16 bf16x8 __attribute__((ext_vector_type(8)));
typedef float f32x4 __attribute__((ext_vector_type(4)));
typedef unsigned short u16x4 __attribute__((ext_vector_type(4)));

#define AS1 __attribute__((address_space(1)))
#define AS3 __attribute__((address_space(3)))

__device__ __forceinline__ unsigned short f2bf(float f) {
    union { float f; unsigned int i; } v; v.f = f;
    unsigned int r = v.i + 0x7fffu + ((v.i >> 16) & 1u);
    return (unsigned short)(r >> 16);
}
__device__ __forceinline__ float sigm(float x) { return 1.f / (1.f + __expf(-x)); }
__device__ __forceinline__ float tanh_(float x) { float e = __expf(2.f * x); return 1.f - 2.f / (e + 1.f); }

// ---------------- spec f32 -> bf16, three destinations (flat, A_cat3, A_cat2)
__global__ __launch_bounds__(256) void cvt_spec3(
    const float* __restrict__ spec, unsigned short* __restrict__ sB,
    unsigned short* __restrict__ X, unsigned short* __restrict__ Y, long n4)
{
    const long stride = (long)gridDim.x * blockDim.x;
    for (long i = (long)blockIdx.x * blockDim.x + threadIdx.x; i < n4; i += stride) {
        const float4 v = ((const float4*)spec)[i];
        u16x4 o; o.x = f2bf(v.x); o.y = f2bf(v.y); o.z = f2bf(v.z); o.w = f2bf(v.w);
        ((u16x4*)sB)[i] = o;
        const long b = i >> 9;            // 512 granules per 2048-el row
        const int c4 = (int)(i & 511);
        *(u16x4*)(X + (b * 4 + (c4 >> 7)) * 768  + ((c4 & 127) << 2)) = o;
        *(u16x4*)(Y + (b * 2 + (c4 >> 8)) * 1536 + ((c4 & 255) << 2)) = o;
    }
}

// ---------------- spec f32 -> bf16 rows of A_cat1 (ld 3072)
__global__ __launch_bounds__(256) void cvt_specA(
    const float* __restrict__ spec, unsigned short* __restrict__ dst, long n4)
{
    const long stride = (long)gridDim.x * blockDim.x;
    for (long i = (long)blockIdx.x * blockDim.x + threadIdx.x; i < n4; i += stride) {
        const float4 v = ((const float4*)spec)[i];
        const long m = i >> 9;
        const int col = ((int)(i & 511)) << 2;
        u16x4 o; o.x = f2bf(v.x); o.y = f2bf(v.y); o.z = f2bf(v.z); o.w = f2bf(v.w);
        *(u16x4*)(dst + m * 3072 + col) = o;
    }
}

// ---------------- merged weight convert+permute (7 segments)
struct PSeg { const float* src; unsigned short* dst; long g0; int H; int kshift; int dstld; int dstcol; };
struct PArgs { PSeg s[7]; long total; };

__global__ __launch_bounds__(256) void cvt_permW_all(PArgs pa)
{
    const long stride = (long)gridDim.x * blockDim.x;
    for (long gi = (long)blockIdx.x * blockDim.x + threadIdx.x; gi < pa.total; gi += stride) {
        int si = 0;
#pragma unroll
        for (int k = 1; k < 7; ++k) si += (gi >= pa.s[k].g0);
        const PSeg sg = pa.s[si];
        const long i = gi - sg.g0;
        const int kq = 1 << sg.kshift;
        const int p = (int)(i >> sg.kshift);
        const int kk = ((int)i & (kq - 1)) << 2;
        const int o = ((p >> 6) << 4) | (p & 15);
        const int q = (p >> 4) & 3;
        const long r = (long)q * sg.H + o;
        const float4 v = *(const float4*)(sg.src + (r << (sg.kshift + 2)) + kk);
        u16x4 wv; wv.x = f2bf(v.x); wv.y = f2bf(v.y); wv.z = f2bf(v.z); wv.w = f2bf(v.w);
        *(u16x4*)(sg.dst + (long)p * sg.dstld + sg.dstcol + kk) = wv;
    }
}

// ---------------- merged combined+permuted biases (4 levels, 7680 elems)
__global__ __launch_bounds__(256) void bias_all(
    const float* __restrict__ bih1, const float* __restrict__ bhh1,
    const float* __restrict__ bih2, const float* __restrict__ bhh2,
    const float* __restrict__ bih3, const float* __restrict__ bhh3,
    const float* __restrict__ bih4, const float* __restrict__ bhh4,
    float* __restrict__ bs1, float* __restrict__ bs2,
    float* __restrict__ bs3, float* __restrict__ bs4)
{
    const int i = blockIdx.x * 256 + threadIdx.x;
    const float *bih, *bhh; float* dst; int H, j;
    if (i < 4096)      { bih = bih1; bhh = bhh1; dst = bs1; H = 1024; j = i; }
    else if (i < 6144) { bih = bih2; bhh = bhh2; dst = bs2; H = 512;  j = i - 4096; }
    else if (i < 7168) { bih = bih3; bhh = bhh3; dst = bs3; H = 256;  j = i - 6144; }
    else               { bih = bih4; bhh = bhh4; dst = bs4; H = 128;  j = i - 7168; }
    const int o = ((j >> 6) << 4) | (j & 15);
    const int q = (j >> 4) & 3;
    dst[j] = bih[q * H + o] + bhh[q * H + o];
}

// ---------------- 256x256 2-phase fused GEMM+LSTM-cell
#define QUAD(S, NS, BF)                                                                     \
    { _Pragma("unroll") for (int mi = 0; mi < 4; ++mi) {                                    \
        _Pragma("unroll") for (int ni = 0; ni < 2; ++ni) {                                  \
            acc[(S)*4+mi][(NS)*2+ni] = __builtin_amdgcn_mfma_f32_16x16x32_bf16(             \
                aF[mi][0], BF[ni][0], acc[(S)*4+mi][(NS)*2+ni], 0, 0, 0);                   \
            acc[(S)*4+mi][(NS)*2+ni] = __builtin_amdgcn_mfma_f32_16x16x32_bf16(             \
                aF[mi][1], BF[ni][1], acc[(S)*4+mi][(NS)*2+ni], 0, 0, 0);                   \
    } } }

#define GLL(gsrc, loff) __builtin_amdgcn_global_load_lds(                                   \
    (const AS1 void*)(gsrc), (AS3 void*)(lds + (loff)), 16, 0, 0)

#define FENCE asm volatile("" ::: "memory")

template<bool HAS_CIN, bool LAST>
__global__ __launch_bounds__(512, 2) void gemm8(
    const unsigned short* __restrict__ A, const unsigned short* __restrict__ W, const int K,
    const float* __restrict__ bsum, const float* __restrict__ Cin,
    float* __restrict__ Hout, float* __restrict__ Cout, const int H)
{
    __shared__ __align__(16) char lds[131072];
    const int t = threadIdx.x;
    const int w = t >> 6, l = t & 63;
    const int wr = w >> 2, wc = w & 3;                 // 2 x 4 wave grid

    // T1: bijective XCD swizzle (nwg always a multiple of 8 here); bx-major
    const int GX = gridDim.x, GY = gridDim.y;
    const int nwg = GX * GY;
    const int bid = (int)blockIdx.y * GX + (int)blockIdx.x;
    const int swz = (bid & 7) * (nwg >> 3) + (bid >> 3);
    const int m0 = (swz / GY) * 256, n0 = (swz % GY) * 256;

    const int colsw = ((l & 7) ^ (l >> 3)) * 8;        // swizzled source col granule
    const size_t k128 = (size_t)128 * K;
    const size_t aoff0 = (size_t)(m0 + w * 16 + (l >> 3)) * K + colsw;
    const size_t aoff1 = aoff0 + (size_t)8 * K;
    const size_t boff0 = (size_t)(n0 + w * 16 + (l >> 3)) * K + colsw;
    const size_t boff1 = boff0 + (size_t)8 * K;
    const int sd0 = w * 2048 + l * 16;                 // LDS byte dest (within region)
    const int sd1 = sd0 + 1024;

    const int lr128 = (l & 15) * 128;
    const int sw0 = (((l >> 4)    ) ^ (l & 7)) * 16;   // swizzled ds_read granules
    const int sw1 = (((l >> 4) + 4) ^ (l & 7)) * 16;

    f32x4 acc[8][4];
#pragma unroll
    for (int i = 0; i < 8; ++i)
#pragma unroll
        for (int j = 0; j < 4; ++j) acc[i][j] = (f32x4){0.f, 0.f, 0.f, 0.f};

    const int NT = K >> 6;   // >= 4 for all levels

    // ---- prologue: tile0 all 4 halves; tile1 B halves (A(1) staged in iter 0)
    GLL(A + aoff0, sd0);                      GLL(A + aoff1, sd1);                 // A0(0)
    GLL(A + aoff0 + k128, 16384 + sd0);       GLL(A + aoff1 + k128, 16384 + sd1);  // A1(0)
    GLL(W + boff0, 32768 + sd0);              GLL(W + boff1, 32768 + sd1);         // B0(0)
    GLL(W + boff0 + k128, 49152 + sd0);       GLL(W + boff1 + k128, 49152 + sd1);  // B1(0)
    GLL(W + boff0 + 64, 98304 + sd0);         GLL(W + boff1 + 64, 98304 + sd1);    // B0(1)
    GLL(W + boff0 + k128 + 64, 114688 + sd0); GLL(W + boff1 + k128 + 64, 114688 + sd1); // B1(1)

    bf16x8 aF[4][2], bF0[2][2], bF1[2][2];

    for (int tt = 0; tt < NT; ++tt) {
        const int q = tt & 1, qn = q ^ 1;
        const int rbA = (q << 16) + (wr << 14) + lr128;
        const int rbB = (q << 16) + 32768 + wc * 8192 + lr128;
        const bool st1 = (tt + 1 < NT), st2 = (tt + 2 < NT);

        // ---- top rendezvous: force tile-t halves landed; sync all waves
        if (st1) { asm volatile("s_waitcnt vmcnt(4)" ::: "memory"); }
        else     { asm volatile("s_waitcnt vmcnt(0)" ::: "memory"); }
        __builtin_amdgcn_s_barrier();
        FENCE;

        // ---- phase A: reads A-lo + B-lo + B-hi; stage A(t+1)->qn; MFMA Q00,Q01
#pragma unroll
        for (int mi = 0; mi < 4; ++mi) {
            aF[mi][0] = *(const bf16x8*)(lds + rbA + mi * 2048 + sw0);
            aF[mi][1] = *(const bf16x8*)(lds + rbA + mi * 2048 + sw1);
        }
#pragma unroll
        for (int ni = 0; ni < 2; ++ni) {
            bF0[ni][0] = *(const bf16x8*)(lds + rbB + ni * 2048 + sw0);
            bF0[ni][1] = *(const bf16x8*)(lds + rbB + ni * 2048 + sw1);
            bF1[ni][0] = *(const bf16x8*)(lds + rbB + 4096 + ni * 2048 + sw0);
            bF1[ni][1] = *(const bf16x8*)(lds + rbB + 4096 + ni * 2048 + sw1);
        }
        if (st1) {   // safe: BARRIER_A arrival proves all tile t-1 reads served
            const size_t ko1 = (size_t)(tt + 1) * 64;
            GLL(A + aoff0 + ko1, (qn << 16) + sd0);
            GLL(A + aoff1 + ko1, (qn << 16) + sd1);
            GLL(A + aoff0 + k128 + ko1, (qn << 16) + 16384 + sd0);
            GLL(A + aoff1 + k128 + ko1, (qn << 16) + 16384 + sd1);
        }
        __builtin_amdgcn_s_setprio(1);
        QUAD(0, 0, bF0);
        QUAD(0, 1, bF1);
        __builtin_amdgcn_s_setprio(0);
        // A-hi reads drain under the MFMA burst above (no fence between)
#pragma unroll
        for (int mi = 0; mi < 4; ++mi) {
            aF[mi][0] = *(const bf16x8*)(lds + rbA + 8192 + mi * 2048 + sw0);
            aF[mi][1] = *(const bf16x8*)(lds + rbA + 8192 + mi * 2048 + sw1);
        }
        __builtin_amdgcn_s_barrier();
        FENCE;

        // ---- phase B: stage B(t+2)->q (safe: Q00/Q01 issued => B reads served);
        //      MFMA Q11,Q10
        if (st2) {
            const size_t ko2 = (size_t)(tt + 2) * 64;
            GLL(W + boff0 + ko2, (q << 16) + 32768 + sd0);
            GLL(W + boff1 + ko2, (q << 16) + 32768 + sd1);
            GLL(W + boff0 + k128 + ko2, (q << 16) + 49152 + sd0);
            GLL(W + boff1 + k128 + ko2, (q << 16) + 49152 + sd1);
        }
        __builtin_amdgcn_s_setprio(1);
        QUAD(1, 1, bF1);
        QUAD(1, 0, bF0);
        __builtin_amdgcn_s_setprio(0);
    }

    // ---- fused LSTM-cell epilogue
    const int ocol = (n0 >> 6) * 16 + wc * 16 + (l & 15);
    const int bb = n0 + wc * 64 + (l & 15);
    const float b0 = bsum[bb], b1 = bsum[bb + 16], b2 = bsum[bb + 32], b3 = bsum[bb + 48];
    const int mrow0 = m0 + wr * 128 + (l >> 4) * 4;
#pragma unroll
    for (int mi = 0; mi < 8; ++mi)
#pragma unroll
        for (int j = 0; j < 4; ++j) {
            const size_t m = (size_t)(mrow0 + mi * 16 + j);
            const float gi = acc[mi][0][j] + b0;
            const float gf = acc[mi][1][j] + b1;
            const float gg = acc[mi][2][j] + b2;
            const float go = acc[mi][3][j] + b3;
            float c2 = sigm(gi) * tanh_(gg);
            if (HAS_CIN) c2 += sigm(gf) * Cin[m * H + ocol];
            const float h2 = sigm(go) * tanh_(c2);
            Hout[m * H + ocol] = h2;
            if (!LAST) Cout[m * H + ocol] = c2;
        }
}

// ---------------- conv1d(k=3,pad=1)+softmax for h AND c in one launch
// blocks [0,nrows): h -> bf16 strided dst; [nrows,2*nrows): c -> f32 dst
template<int L>
__global__ __launch_bounds__(256) void conv_dual(
    const float* __restrict__ Hin, const float* __restrict__ Cin,
    const float* __restrict__ w3h, const float* __restrict__ w3c,
    unsigned short* __restrict__ Yb, int ldYb, float* __restrict__ cbuf)
{
    __shared__ float xs[L + 2];
    __shared__ float red[8];
    const int nrows = gridDim.x >> 1;
    const bool isC = (int)blockIdx.x >= nrows;
    const int row = isC ? ((int)blockIdx.x - nrows) : (int)blockIdx.x;
    const float* Xs = isC ? Cin : Hin;
    const float* w3 = isC ? w3c : w3h;
    const int t = threadIdx.x;
    const size_t base = (size_t)row * L;
    const float w0 = w3[0], w1 = w3[1], w2 = w3[2];
    if (t == 0) { xs[0] = 0.f; xs[L + 1] = 0.f; }
    for (int i = t; i < L; i += 256) xs[i + 1] = Xs[base + i];
    __syncthreads();
    constexpr int E = L / 256;
    float y[E];
    float vmax = -3.4e38f;
#pragma unroll
    for (int i = 0; i < E; ++i) {
        const int c = t + i * 256;
        y[i] = w0 * xs[c] + w1 * xs[c + 1] + w2 * xs[c + 2];
        vmax = fmaxf(vmax, y[i]);
    }
#pragma unroll
    for (int off = 32; off >= 1; off >>= 1) vmax = fmaxf(vmax, __shfl_xor(vmax, off));
    if ((t & 63) == 0) red[t >> 6] = vmax;
    __syncthreads();
    vmax = fmaxf(fmaxf(red[0], red[1]), fmaxf(red[2], red[3]));
    float s = 0.f;
#pragma unroll
    for (int i = 0; i < E; ++i) { y[i] = __expf(y[i] - vmax); s += y[i]; }
#pragma unroll
    for (int off = 32; off >= 1; off >>= 1) s += __shfl_xor(s, off);
    if ((t & 63) == 0) red[4 + (t >> 6)] = s;
    __syncthreads();
    const float inv = 1.f / (red[4] + red[5] + red[6] + red[7]);
#pragma unroll
    for (int i = 0; i < E; ++i) {
        const int c = t + i * 256;
        const float v = y[i] * inv;
        if (isC) cbuf[base + c] = v;
        else     Yb[(size_t)row * ldYb + c] = f2bf(v);
    }
}

extern "C" void kernel_launch(void* const* d_in, const int* in_sizes, int n_in,
                              void* d_out, int out_size, void* d_ws, size_t ws_size,
                              hipStream_t stream)
{
    (void)in_sizes; (void)n_in; (void)out_size; (void)ws_size;
    const float* spec  = (const float*)d_in[0];
    const float* Wih1  = (const float*)d_in[1];
    const float* Whh1  = (const float*)d_in[2];
    const float* bih1  = (const float*)d_in[3];
    const float* bhh1  = (const float*)d_in[4];
    const float* Wih2  = (const float*)d_in[5];
    const float* Whh2  = (const float*)d_in[6];
    const float* bih2  = (const float*)d_in[7];
    const float* bhh2  = (const float*)d_in[8];
    const float* Wih3  = (const float*)d_in[9];
    const float* Whh3  = (const float*)d_in[10];
    const float* bih3  = (const float*)d_in[11];
    const float* bhh3  = (const float*)d_in[12];
    const float* Wih4  = (const float*)d_in[13];
    const float* bih4  = (const float*)d_in[15];
    const float* bhh4  = (const float*)d_in[16];
    const float* w2_1h = (const float*)d_in[17];
    const float* w2_1c = (const float*)d_in[18];
    const float* w3_2h = (const float*)d_in[19];
    const float* w3_2c = (const float*)d_in[20];
    const float* w4_3h = (const float*)d_in[21];
    const float* w4_3c = (const float*)d_in[22];

    char* ws = (char*)d_ws;
    float*          h   = (float*)(ws + 0);                         // 16 MiB
    float*          c   = (float*)(ws + (size_t)16777216);          // 16 MiB
    float*          cb  = (float*)(ws + (size_t)33554432);          // 16 MiB
    unsigned short* sB  = (unsigned short*)(ws + (size_t)50331648); // 16 MiB (spec bf16, L4 A)
    unsigned short* X   = (unsigned short*)(ws + (size_t)67108864); // 24 MiB (A_cat3 -> A_cat1)
    unsigned short* Y   = (unsigned short*)(ws + (size_t)92274688); // 24 MiB (A_cat2)
    unsigned short* Wc1 = (unsigned short*)(ws + (size_t)117440512);// 24 MiB
    unsigned short* Wc2 = (unsigned short*)(ws + (size_t)142606336);//  6 MiB
    unsigned short* Wc3 = (unsigned short*)(ws + (size_t)148897792);// 1.5 MiB
    unsigned short* W4  = (unsigned short*)(ws + (size_t)150470656);// 0.25 MiB
    float*          bs1 = (float*)(ws + (size_t)150732800);
    float*          bs2 = bs1 + 4096;
    float*          bs3 = bs2 + 4096;
    float*          bs4 = bs3 + 4096;

    // ---- conversions (Whh4 unused: level-4 h_in == 0)
    cvt_spec3<<<2048, 256, 0, stream>>>(spec, sB, X, Y, 2097152);
    PArgs pa;
    pa.s[0] = { Wih1, Wc1,       0, 1024, 9, 3072,    0 };
    pa.s[1] = { Whh1, Wc1, 2097152, 1024, 8, 3072, 2048 };
    pa.s[2] = { Wih2, Wc2, 3145728,  512, 8, 1536,    0 };
    pa.s[3] = { Whh2, Wc2, 3670016,  512, 7, 1536, 1024 };
    pa.s[4] = { Wih3, Wc3, 3932160,  256, 7,  768,    0 };
    pa.s[5] = { Whh3, Wc3, 4063232,  256, 6,  768,  512 };
    pa.s[6] = { Wih4, W4,  4128768,  128, 6,  256,    0 };
    pa.total = 4161536;
    cvt_permW_all<<<2048, 256, 0, stream>>>(pa);
    bias_all<<<30, 256, 0, stream>>>(bih1, bhh1, bih2, bhh2, bih3, bhh3, bih4, bhh4,
                                     bs1, bs2, bs3, bs4);

    // ---- Level 4: M=32768, N=512 (H=128), K=256
    gemm8<false, false><<<dim3(128, 2), 512, 0, stream>>>(sB, W4, 256, bs4, nullptr, h, c, 128);
    conv_dual<256><<<32768, 256, 0, stream>>>(h, c, w4_3h, w4_3c, X + 512, 768, cb);

    // ---- Level 3: M=16384, N=1024 (H=256), K=768
    gemm8<true, false><<<dim3(64, 4), 512, 0, stream>>>(X, Wc3, 768, bs3, cb, h, c, 256);
    cvt_specA<<<2048, 256, 0, stream>>>(spec, X, 2097152);     // A_cat1 spec part (X@768 free)
    conv_dual<512><<<16384, 256, 0, stream>>>(h, c, w3_2h, w3_2c, Y + 1024, 1536, cb);

    // ---- Level 2: M=8192, N=2048 (H=512), K=1536
    gemm8<true, false><<<dim3(32, 8), 512, 0, stream>>>(Y, Wc2, 1536, bs2, cb, h, c, 512);
    conv_dual<1024><<<8192, 256, 0, stream>>>(h, c, w2_1h, w2_1c, X + 2048, 3072, cb);

    // ---- Level 1: M=4096, N=4096 (H=1024), K=3072; h1 -> d_out (f32)
    gemm8<true, true><<<dim3(16, 16), 512, 0, stream>>>(X, Wc1, 3072, bs1, cb, (float*)d_out, nullptr, 1024);
}

// Round 7
// 331.587 us; speedup vs baseline: 1.0076x; 1.0076x over previous
//
#include <hip/hip_runtime.h>

// B=4096, ID=2048, OD=1024. 4-level pyramidal LSTM, f32 I/O.
// GEMM: 256x256 tile, 32x32x16 MFMA (2x FLOP/instr vs 16x16x32), 2-phase/K-tile,
// counted vmcnt(4), T2 LDS swizzle, T5 setprio, T1 XCD swizzle. LSTM cell fused
// in epilogue via gate-interleaved weight permutation:
//   W row p <- orig row q*H+o, with p = 128*(o>>5) + 32*q + (o&31).
// Wave grid 4m x 2n (wave tile 64x128): lane owns cols o=(l&31) of one 128-col
// gate group -> acc[mi][q][reg] = gate q of output o, no cross-lane epilogue.

typedef __bf16 bf16x8 __attribute__((ext_vector_type(8)));
typedef float f32x16 __attribute__((ext_vector_type(16)));
typedef unsigned short u16x4 __attribute__((ext_vector_type(4)));

#define AS1 __attribute__((address_space(1)))
#define AS3 __attribute__((address_space(3)))

__device__ __forceinline__ unsigned short f2bf(float f) {
    union { float f; unsigned int i; } v; v.f = f;
    unsigned int r = v.i + 0x7fffu + ((v.i >> 16) & 1u);
    return (unsigned short)(r >> 16);
}
__device__ __forceinline__ float sigm(float x) { return 1.f / (1.f + __expf(-x)); }
__device__ __forceinline__ float tanh_(float x) { float e = __expf(2.f * x); return 1.f - 2.f / (e + 1.f); }

// ---------------- spec f32 -> bf16, three destinations (flat, A_cat3, A_cat2)
__global__ __launch_bounds__(256) void cvt_spec3(
    const float* __restrict__ spec, unsigned short* __restrict__ sB,
    unsigned short* __restrict__ X, unsigned short* __restrict__ Y, long n4)
{
    const long stride = (long)gridDim.x * blockDim.x;
    for (long i = (long)blockIdx.x * blockDim.x + threadIdx.x; i < n4; i += stride) {
        const float4 v = ((const float4*)spec)[i];
        u16x4 o; o.x = f2bf(v.x); o.y = f2bf(v.y); o.z = f2bf(v.z); o.w = f2bf(v.w);
        ((u16x4*)sB)[i] = o;
        const long b = i >> 9;            // 512 granules per 2048-el row
        const int c4 = (int)(i & 511);
        *(u16x4*)(X + (b * 4 + (c4 >> 7)) * 768  + ((c4 & 127) << 2)) = o;
        *(u16x4*)(Y + (b * 2 + (c4 >> 8)) * 1536 + ((c4 & 255) << 2)) = o;
    }
}

// ---------------- spec f32 -> bf16 rows of A_cat1 (ld 3072)
__global__ __launch_bounds__(256) void cvt_specA(
    const float* __restrict__ spec, unsigned short* __restrict__ dst, long n4)
{
    const long stride = (long)gridDim.x * blockDim.x;
    for (long i = (long)blockIdx.x * blockDim.x + threadIdx.x; i < n4; i += stride) {
        const float4 v = ((const float4*)spec)[i];
        const long m = i >> 9;
        const int col = ((int)(i & 511)) << 2;
        u16x4 o; o.x = f2bf(v.x); o.y = f2bf(v.y); o.z = f2bf(v.z); o.w = f2bf(v.w);
        *(u16x4*)(dst + m * 3072 + col) = o;
    }
}

// ---------------- merged weight convert+permute (7 segments)
// dst row p <- src row q*H+o : o = ((p>>7)<<5)|(p&31), q = (p>>5)&3
struct PSeg { const float* src; unsigned short* dst; long g0; int H; int kshift; int dstld; int dstcol; };
struct PArgs { PSeg s[7]; long total; };

__global__ __launch_bounds__(256) void cvt_permW_all(PArgs pa)
{
    const long stride = (long)gridDim.x * blockDim.x;
    for (long gi = (long)blockIdx.x * blockDim.x + threadIdx.x; gi < pa.total; gi += stride) {
        int si = 0;
#pragma unroll
        for (int k = 1; k < 7; ++k) si += (gi >= pa.s[k].g0);
        const PSeg sg = pa.s[si];
        const long i = gi - sg.g0;
        const int kq = 1 << sg.kshift;
        const int p = (int)(i >> sg.kshift);
        const int kk = ((int)i & (kq - 1)) << 2;
        const int o = ((p >> 7) << 5) | (p & 31);
        const int q = (p >> 5) & 3;
        const long r = (long)q * sg.H + o;
        const float4 v = *(const float4*)(sg.src + (r << (sg.kshift + 2)) + kk);
        u16x4 wv; wv.x = f2bf(v.x); wv.y = f2bf(v.y); wv.z = f2bf(v.z); wv.w = f2bf(v.w);
        *(u16x4*)(sg.dst + (long)p * sg.dstld + sg.dstcol + kk) = wv;
    }
}

// ---------------- merged combined+permuted biases (4 levels, 7680 elems)
__global__ __launch_bounds__(256) void bias_all(
    const float* __restrict__ bih1, const float* __restrict__ bhh1,
    const float* __restrict__ bih2, const float* __restrict__ bhh2,
    const float* __restrict__ bih3, const float* __restrict__ bhh3,
    const float* __restrict__ bih4, const float* __restrict__ bhh4,
    float* __restrict__ bs1, float* __restrict__ bs2,
    float* __restrict__ bs3, float* __restrict__ bs4)
{
    const int i = blockIdx.x * 256 + threadIdx.x;
    const float *bih, *bhh; float* dst; int H, j;
    if (i < 4096)      { bih = bih1; bhh = bhh1; dst = bs1; H = 1024; j = i; }
    else if (i < 6144) { bih = bih2; bhh = bhh2; dst = bs2; H = 512;  j = i - 4096; }
    else if (i < 7168) { bih = bih3; bhh = bhh3; dst = bs3; H = 256;  j = i - 6144; }
    else               { bih = bih4; bhh = bhh4; dst = bs4; H = 128;  j = i - 7168; }
    const int o = ((j >> 7) << 5) | (j & 31);
    const int q = (j >> 5) & 3;
    dst[j] = bih[q * H + o] + bhh[q * H + o];
}

// ---------------- 256x256 2-phase fused GEMM+LSTM-cell (32x32x16 MFMA)
#define GLL(gsrc, loff) __builtin_amdgcn_global_load_lds(                                   \
    (const AS1 void*)(gsrc), (AS3 void*)(lds + (loff)), 16, 0, 0)

#define FENCE asm volatile("" ::: "memory")

template<bool HAS_CIN, bool LAST>
__global__ __launch_bounds__(512, 2) void gemm8(
    const unsigned short* __restrict__ A, const unsigned short* __restrict__ W, const int K,
    const float* __restrict__ bsum, const float* __restrict__ Cin,
    float* __restrict__ Hout, float* __restrict__ Cout, const int H)
{
    __shared__ __align__(16) char lds[131072];
    const int t = threadIdx.x;
    const int w = t >> 6, l = t & 63;
    const int wr = w >> 1, wc = w & 1;                 // 4m x 2n wave grid

    // T1: bijective XCD swizzle (nwg always a multiple of 8 here); bx-major
    const int GX = gridDim.x, GY = gridDim.y;
    const int nwg = GX * GY;
    const int bid = (int)blockIdx.y * GX + (int)blockIdx.x;
    const int swz = (bid & 7) * (nwg >> 3) + (bid >> 3);
    const int m0 = (swz / GY) * 256, n0 = (swz % GY) * 256;

    const int colsw = ((l & 7) ^ (l >> 3)) * 8;        // swizzled source col granule
    const size_t k128 = (size_t)128 * K;
    const size_t aoff0 = (size_t)(m0 + w * 16 + (l >> 3)) * K + colsw;
    const size_t aoff1 = aoff0 + (size_t)8 * K;
    const size_t boff0 = (size_t)(n0 + w * 16 + (l >> 3)) * K + colsw;
    const size_t boff1 = boff0 + (size_t)8 * K;
    const int sd0 = w * 2048 + l * 16;                 // LDS byte dest (within region)
    const int sd1 = sd0 + 1024;

    // ds_read: row (l&31)*128B; k-granule for slice ks: ((ks*2+(l>>5)) ^ (l&7))*16
    const int lrow = (l & 31) * 128;
    int gsw[8];
#pragma unroll
    for (int ks = 0; ks < 4; ++ks) {
        gsw[ks * 2]     = (((ks << 1) | (l >> 5)) ^ (l & 7)) << 4;
    }

    f32x16 acc[2][4];
#pragma unroll
    for (int i = 0; i < 2; ++i)
#pragma unroll
        for (int j = 0; j < 4; ++j)
#pragma unroll
            for (int e = 0; e < 16; ++e) acc[i][j][e] = 0.f;

    const int NT = K >> 6;   // >= 4 for all levels

    // ---- prologue: tile0 A+B; tile1 B (A(1) staged in iter 0 phase A)
    GLL(A + aoff0, sd0);                      GLL(A + aoff1, sd1);                 // A(0) h0
    GLL(A + aoff0 + k128, 16384 + sd0);       GLL(A + aoff1 + k128, 16384 + sd1);  // A(0) h1
    GLL(W + boff0, 32768 + sd0);              GLL(W + boff1, 32768 + sd1);         // B(0) h0
    GLL(W + boff0 + k128, 49152 + sd0);       GLL(W + boff1 + k128, 49152 + sd1);  // B(0) h1
    GLL(W + boff0 + 64, 98304 + sd0);         GLL(W + boff1 + 64, 98304 + sd1);    // B(1) h0
    GLL(W + boff0 + k128 + 64, 114688 + sd0); GLL(W + boff1 + k128 + 64, 114688 + sd1); // B(1) h1

    bf16x8 aF[2][4], bF0[2][4], bF1[2][4];

    for (int tt = 0; tt < NT; ++tt) {
        const int q = tt & 1, qn = q ^ 1;
        const int rbA = (q << 16) + (wr << 13) + lrow;
        const int rbB = (q << 16) + 32768 + (wc << 14) + lrow;
        const bool st1 = (tt + 1 < NT), st2 = (tt + 2 < NT);

        // ---- top rendezvous: force tile-t halves landed; sync all waves
        if (st1) { asm volatile("s_waitcnt vmcnt(4)" ::: "memory"); }
        else     { asm volatile("s_waitcnt vmcnt(0)" ::: "memory"); }
        __builtin_amdgcn_s_barrier();
        FENCE;

        // ---- phase A: read A(8) + B-lo(8); stage A(t+1)->qn; MFMA n-blocks 0,1
#pragma unroll
        for (int ks = 0; ks < 4; ++ks) {
#pragma unroll
            for (int mi = 0; mi < 2; ++mi)
                aF[mi][ks] = *(const bf16x8*)(lds + rbA + (mi << 12) + gsw[ks * 2]);
#pragma unroll
            for (int ni = 0; ni < 2; ++ni)
                bF0[ni][ks] = *(const bf16x8*)(lds + rbB + (ni << 12) + gsw[ks * 2]);
        }
        if (st1) {   // safe: barrier arrival proves all tile t-1 reads served
            const size_t ko1 = (size_t)(tt + 1) * 64;
            GLL(A + aoff0 + ko1, (qn << 16) + sd0);
            GLL(A + aoff1 + ko1, (qn << 16) + sd1);
            GLL(A + aoff0 + k128 + ko1, (qn << 16) + 16384 + sd0);
            GLL(A + aoff1 + k128 + ko1, (qn << 16) + 16384 + sd1);
        }
        __builtin_amdgcn_s_setprio(1);
#pragma unroll
        for (int ks = 0; ks < 4; ++ks)
#pragma unroll
            for (int mi = 0; mi < 2; ++mi)
#pragma unroll
                for (int ni = 0; ni < 2; ++ni)
                    acc[mi][ni] = __builtin_amdgcn_mfma_f32_32x32x16_bf16(
                        aF[mi][ks], bF0[ni][ks], acc[mi][ni], 0, 0, 0);
        __builtin_amdgcn_s_setprio(0);
        __builtin_amdgcn_s_barrier();
        FENCE;

        // ---- phase B: read B-hi(8); stage B(t+2)->q; MFMA n-blocks 2,3
#pragma unroll
        for (int ks = 0; ks < 4; ++ks)
#pragma unroll
            for (int ni = 0; ni < 2; ++ni)
                bF1[ni][ks] = *(const bf16x8*)(lds + rbB + ((ni + 2) << 12) + gsw[ks * 2]);
        if (st2) {
            const size_t ko2 = (size_t)(tt + 2) * 64;
            GLL(W + boff0 + ko2, (q << 16) + 32768 + sd0);
            GLL(W + boff1 + ko2, (q << 16) + 32768 + sd1);
            GLL(W + boff0 + k128 + ko2, (q << 16) + 49152 + sd0);
            GLL(W + boff1 + k128 + ko2, (q << 16) + 49152 + sd1);
        }
        __builtin_amdgcn_s_setprio(1);
#pragma unroll
        for (int ks = 0; ks < 4; ++ks)
#pragma unroll
            for (int mi = 0; mi < 2; ++mi)
#pragma unroll
                for (int ni = 0; ni < 2; ++ni)
                    acc[mi][ni + 2] = __builtin_amdgcn_mfma_f32_32x32x16_bf16(
                        aF[mi][ks], bF1[ni][ks], acc[mi][ni + 2], 0, 0, 0);
        __builtin_amdgcn_s_setprio(0);
    }

    // ---- fused LSTM-cell epilogue: wave's 128-col group = 4 gates x 32 outputs
    // C layout (m74/m101): col=lane&31, row=(reg&3)+8*(reg>>2)+4*(lane>>5)
    const int ncol0 = n0 + (wc << 7);
    const int ocol = ((ncol0 >> 7) << 5) + (l & 31);
    const float b0 = bsum[ncol0 +      (l & 31)];
    const float b1 = bsum[ncol0 + 32 + (l & 31)];
    const float b2 = bsum[ncol0 + 64 + (l & 31)];
    const float b3 = bsum[ncol0 + 96 + (l & 31)];
    const int mrow0 = m0 + (wr << 6) + ((l >> 5) << 2);
#pragma unroll
    for (int mi = 0; mi < 2; ++mi)
#pragma unroll
        for (int reg = 0; reg < 16; ++reg) {
            const size_t m = (size_t)(mrow0 + (mi << 5) + (reg & 3) + ((reg >> 2) << 3));
            const float gi = acc[mi][0][reg] + b0;
            const float gf = acc[mi][1][reg] + b1;
            const float gg = acc[mi][2][reg] + b2;
            const float go = acc[mi][3][reg] + b3;
            float c2 = sigm(gi) * tanh_(gg);
            if (HAS_CIN) c2 += sigm(gf) * Cin[m * H + ocol];
            const float h2 = sigm(go) * tanh_(c2);
            Hout[m * H + ocol] = h2;
            if (!LAST) Cout[m * H + ocol] = c2;
        }
}

// ---------------- conv1d(k=3,pad=1)+softmax for h AND c in one launch
template<int L>
__global__ __launch_bounds__(256) void conv_dual(
    const float* __restrict__ Hin, const float* __restrict__ Cin,
    const float* __restrict__ w3h, const float* __restrict__ w3c,
    unsigned short* __restrict__ Yb, int ldYb, float* __restrict__ cbuf)
{
    __shared__ float xs[L + 2];
    __shared__ float red[8];
    const int nrows = gridDim.x >> 1;
    const bool isC = (int)blockIdx.x >= nrows;
    const int row = isC ? ((int)blockIdx.x - nrows) : (int)blockIdx.x;
    const float* Xs = isC ? Cin : Hin;
    const float* w3 = isC ? w3c : w3h;
    const int t = threadIdx.x;
    const size_t base = (size_t)row * L;
    const float w0 = w3[0], w1 = w3[1], w2 = w3[2];
    if (t == 0) { xs[0] = 0.f; xs[L + 1] = 0.f; }
    for (int i = t; i < L; i += 256) xs[i + 1] = Xs[base + i];
    __syncthreads();
    constexpr int E = L / 256;
    float y[E];
    float vmax = -3.4e38f;
#pragma unroll
    for (int i = 0; i < E; ++i) {
        const int c = t + i * 256;
        y[i] = w0 * xs[c] + w1 * xs[c + 1] + w2 * xs[c + 2];
        vmax = fmaxf(vmax, y[i]);
    }
#pragma unroll
    for (int off = 32; off >= 1; off >>= 1) vmax = fmaxf(vmax, __shfl_xor(vmax, off));
    if ((t & 63) == 0) red[t >> 6] = vmax;
    __syncthreads();
    vmax = fmaxf(fmaxf(red[0], red[1]), fmaxf(red[2], red[3]));
    float s = 0.f;
#pragma unroll
    for (int i = 0; i < E; ++i) { y[i] = __expf(y[i] - vmax); s += y[i]; }
#pragma unroll
    for (int off = 32; off >= 1; off >>= 1) s += __shfl_xor(s, off);
    if ((t & 63) == 0) red[4 + (t >> 6)] = s;
    __syncthreads();
    const float inv = 1.f / (red[4] + red[5] + red[6] + red[7]);
#pragma unroll
    for (int i = 0; i < E; ++i) {
        const int c = t + i * 256;
        const float v = y[i] * inv;
        if (isC) cbuf[base + c] = v;
        else     Yb[(size_t)row * ldYb + c] = f2bf(v);
    }
}

extern "C" void kernel_launch(void* const* d_in, const int* in_sizes, int n_in,
                              void* d_out, int out_size, void* d_ws, size_t ws_size,
                              hipStream_t stream)
{
    (void)in_sizes; (void)n_in; (void)out_size; (void)ws_size;
    const float* spec  = (const float*)d_in[0];
    const float* Wih1  = (const float*)d_in[1];
    const float* Whh1  = (const float*)d_in[2];
    const float* bih1  = (const float*)d_in[3];
    const float* bhh1  = (const float*)d_in[4];
    const float* Wih2  = (const float*)d_in[5];
    const float* Whh2  = (const float*)d_in[6];
    const float* bih2  = (const float*)d_in[7];
    const float* bhh2  = (const float*)d_in[8];
    const float* Wih3  = (const float*)d_in[9];
    const float* Whh3  = (const float*)d_in[10];
    const float* bih3  = (const float*)d_in[11];
    const float* bhh3  = (const float*)d_in[12];
    const float* Wih4  = (const float*)d_in[13];
    const float* bih4  = (const float*)d_in[15];
    const float* bhh4  = (const float*)d_in[16];
    const float* w2_1h = (const float*)d_in[17];
    const float* w2_1c = (const float*)d_in[18];
    const float* w3_2h = (const float*)d_in[19];
    const float* w3_2c = (const float*)d_in[20];
    const float* w4_3h = (const float*)d_in[21];
    const float* w4_3c = (const float*)d_in[22];

    char* ws = (char*)d_ws;
    float*          h   = (float*)(ws + 0);                         // 16 MiB
    float*          c   = (float*)(ws + (size_t)16777216);          // 16 MiB
    float*          cb  = (float*)(ws + (size_t)33554432);          // 16 MiB
    unsigned short* sB  = (unsigned short*)(ws + (size_t)50331648); // 16 MiB (spec bf16, L4 A)
    unsigned short* X   = (unsigned short*)(ws + (size_t)67108864); // 24 MiB (A_cat3 -> A_cat1)
    unsigned short* Y   = (unsigned short*)(ws + (size_t)92274688); // 24 MiB (A_cat2)
    unsigned short* Wc1 = (unsigned short*)(ws + (size_t)117440512);// 24 MiB
    unsigned short* Wc2 = (unsigned short*)(ws + (size_t)142606336);//  6 MiB
    unsigned short* Wc3 = (unsigned short*)(ws + (size_t)148897792);// 1.5 MiB
    unsigned short* W4  = (unsigned short*)(ws + (size_t)150470656);// 0.25 MiB
    float*          bs1 = (float*)(ws + (size_t)150732800);
    float*          bs2 = bs1 + 4096;
    float*          bs3 = bs2 + 4096;
    float*          bs4 = bs3 + 4096;

    // ---- conversions (Whh4 unused: level-4 h_in == 0)
    cvt_spec3<<<2048, 256, 0, stream>>>(spec, sB, X, Y, 2097152);
    PArgs pa;
    pa.s[0] = { Wih1, Wc1,       0, 1024, 9, 3072,    0 };
    pa.s[1] = { Whh1, Wc1, 2097152, 1024, 8, 3072, 2048 };
    pa.s[2] = { Wih2, Wc2, 3145728,  512, 8, 1536,    0 };
    pa.s[3] = { Whh2, Wc2, 3670016,  512, 7, 1536, 1024 };
    pa.s[4] = { Wih3, Wc3, 3932160,  256, 7,  768,    0 };
    pa.s[5] = { Whh3, Wc3, 4063232,  256, 6,  768,  512 };
    pa.s[6] = { Wih4, W4,  4128768,  128, 6,  256,    0 };
    pa.total = 4161536;
    cvt_permW_all<<<2048, 256, 0, stream>>>(pa);
    bias_all<<<30, 256, 0, stream>>>(bih1, bhh1, bih2, bhh2, bih3, bhh3, bih4, bhh4,
                                     bs1, bs2, bs3, bs4);

    // ---- Level 4: M=32768, N=512 (H=128), K=256
    gemm8<false, false><<<dim3(128, 2), 512, 0, stream>>>(sB, W4, 256, bs4, nullptr, h, c, 128);
    conv_dual<256><<<32768, 256, 0, stream>>>(h, c, w4_3h, w4_3c, X + 512, 768, cb);

    // ---- Level 3: M=16384, N=1024 (H=256), K=768
    gemm8<true, false><<<dim3(64, 4), 512, 0, stream>>>(X, Wc3, 768, bs3, cb, h, c, 256);
    cvt_specA<<<2048, 256, 0, stream>>>(spec, X, 2097152);     // A_cat1 spec part (X@768 free)
    conv_dual<512><<<16384, 256, 0, stream>>>(h, c, w3_2h, w3_2c, Y + 1024, 1536, cb);

    // ---- Level 2: M=8192, N=2048 (H=512), K=1536
    gemm8<true, false><<<dim3(32, 8), 512, 0, stream>>>(Y, Wc2, 1536, bs2, cb, h, c, 512);
    conv_dual<1024><<<8192, 256, 0, stream>>>(h, c, w2_1h, w2_1c, X + 2048, 3072, cb);

    // ---- Level 1: M=4096, N=4096 (H=1024), K=3072; h1 -> d_out (f32)
    gemm8<true, true><<<dim3(16, 16), 512, 0, stream>>>(X, Wc1, 3072, bs1, cb, (float*)d_out, nullptr, 1024);
}

// Round 8
// 309.851 us; speedup vs baseline: 1.0782x; 1.0701x over previous
//
#include <hip/hip_runtime.h>

// B=4096, ID=2048, OD=1024. 4-level pyramidal LSTM, f32 I/O.
// GEMM: 256x256 tile, 16x16x32 MFMA, 2 barriers/K-tile, counted vmcnt(4),
// REGISTER-PIPELINED reads: all 24 ds_reads issued before the MFMA clusters
// (aLo,bF0,bF1,aHi separate regs) so LDS pipe overlaps MFMA pipe via
// compiler fine-grained lgkmcnt. T2 LDS swizzle, T5 setprio, T1 XCD swizzle.
// LSTM cell fused in epilogue via gate-interleaved weight permutation
// (W row p <- q*H+o, p = 64*(o>>4) + 16*q + (o&15)).

typedef __bf16 bf16x8 __attribute__((ext_vector_type(8)));
typedef float f32x4 __attribute__((ext_vector_type(4)));
typedef unsigned short u16x4 __attribute__((ext_vector_type(4)));

#define AS1 __attribute__((address_space(1)))
#define AS3 __attribute__((address_space(3)))

__device__ __forceinline__ unsigned short f2bf(float f) {
    union { float f; unsigned int i; } v; v.f = f;
    unsigned int r = v.i + 0x7fffu + ((v.i >> 16) & 1u);
    return (unsigned short)(r >> 16);
}
__device__ __forceinline__ float sigm(float x) { return 1.f / (1.f + __expf(-x)); }
__device__ __forceinline__ float tanh_(float x) { float e = __expf(2.f * x); return 1.f - 2.f / (e + 1.f); }

// ---------------- spec f32 -> bf16, three destinations (flat, A_cat3, A_cat2)
__global__ __launch_bounds__(256) void cvt_spec3(
    const float* __restrict__ spec, unsigned short* __restrict__ sB,
    unsigned short* __restrict__ X, unsigned short* __restrict__ Y, long n4)
{
    const long stride = (long)gridDim.x * blockDim.x;
    for (long i = (long)blockIdx.x * blockDim.x + threadIdx.x; i < n4; i += stride) {
        const float4 v = ((const float4*)spec)[i];
        u16x4 o; o.x = f2bf(v.x); o.y = f2bf(v.y); o.z = f2bf(v.z); o.w = f2bf(v.w);
        ((u16x4*)sB)[i] = o;
        const long b = i >> 9;            // 512 granules per 2048-el row
        const int c4 = (int)(i & 511);
        *(u16x4*)(X + (b * 4 + (c4 >> 7)) * 768  + ((c4 & 127) << 2)) = o;
        *(u16x4*)(Y + (b * 2 + (c4 >> 8)) * 1536 + ((c4 & 255) << 2)) = o;
    }
}

// ---------------- spec f32 -> bf16 rows of A_cat1 (ld 3072)
__global__ __launch_bounds__(256) void cvt_specA(
    const float* __restrict__ spec, unsigned short* __restrict__ dst, long n4)
{
    const long stride = (long)gridDim.x * blockDim.x;
    for (long i = (long)blockIdx.x * blockDim.x + threadIdx.x; i < n4; i += stride) {
        const float4 v = ((const float4*)spec)[i];
        const long m = i >> 9;
        const int col = ((int)(i & 511)) << 2;
        u16x4 o; o.x = f2bf(v.x); o.y = f2bf(v.y); o.z = f2bf(v.z); o.w = f2bf(v.w);
        *(u16x4*)(dst + m * 3072 + col) = o;
    }
}

// ---------------- merged weight convert+permute (7 segments)
// dst row p <- src row q*H+o : o = ((p>>6)<<4)|(p&15), q = (p>>4)&3
struct PSeg { const float* src; unsigned short* dst; long g0; int H; int kshift; int dstld; int dstcol; };
struct PArgs { PSeg s[7]; long total; };

__global__ __launch_bounds__(256) void cvt_permW_all(PArgs pa)
{
    const long stride = (long)gridDim.x * blockDim.x;
    for (long gi = (long)blockIdx.x * blockDim.x + threadIdx.x; gi < pa.total; gi += stride) {
        int si = 0;
#pragma unroll
        for (int k = 1; k < 7; ++k) si += (gi >= pa.s[k].g0);
        const PSeg sg = pa.s[si];
        const long i = gi - sg.g0;
        const int kq = 1 << sg.kshift;
        const int p = (int)(i >> sg.kshift);
        const int kk = ((int)i & (kq - 1)) << 2;
        const int o = ((p >> 6) << 4) | (p & 15);
        const int q = (p >> 4) & 3;
        const long r = (long)q * sg.H + o;
        const float4 v = *(const float4*)(sg.src + (r << (sg.kshift + 2)) + kk);
        u16x4 wv; wv.x = f2bf(v.x); wv.y = f2bf(v.y); wv.z = f2bf(v.z); wv.w = f2bf(v.w);
        *(u16x4*)(sg.dst + (long)p * sg.dstld + sg.dstcol + kk) = wv;
    }
}

// ---------------- merged combined+permuted biases (4 levels, 7680 elems)
__global__ __launch_bounds__(256) void bias_all(
    const float* __restrict__ bih1, const float* __restrict__ bhh1,
    const float* __restrict__ bih2, const float* __restrict__ bhh2,
    const float* __restrict__ bih3, const float* __restrict__ bhh3,
    const float* __restrict__ bih4, const float* __restrict__ bhh4,
    float* __restrict__ bs1, float* __restrict__ bs2,
    float* __restrict__ bs3, float* __restrict__ bs4)
{
    const int i = blockIdx.x * 256 + threadIdx.x;
    const float *bih, *bhh; float* dst; int H, j;
    if (i < 4096)      { bih = bih1; bhh = bhh1; dst = bs1; H = 1024; j = i; }
    else if (i < 6144) { bih = bih2; bhh = bhh2; dst = bs2; H = 512;  j = i - 4096; }
    else if (i < 7168) { bih = bih3; bhh = bhh3; dst = bs3; H = 256;  j = i - 6144; }
    else               { bih = bih4; bhh = bhh4; dst = bs4; H = 128;  j = i - 7168; }
    const int o = ((j >> 6) << 4) | (j & 15);
    const int q = (j >> 4) & 3;
    dst[j] = bih[q * H + o] + bhh[q * H + o];
}

// ---------------- 256x256 fused GEMM+LSTM-cell, register-pipelined
#define QUAD(AF, S, NS, BF)                                                                 \
    { _Pragma("unroll") for (int mi = 0; mi < 4; ++mi) {                                    \
        _Pragma("unroll") for (int ni = 0; ni < 2; ++ni) {                                  \
            acc[(S)*4+mi][(NS)*2+ni] = __builtin_amdgcn_mfma_f32_16x16x32_bf16(             \
                AF[mi][0], BF[ni][0], acc[(S)*4+mi][(NS)*2+ni], 0, 0, 0);                   \
            acc[(S)*4+mi][(NS)*2+ni] = __builtin_amdgcn_mfma_f32_16x16x32_bf16(             \
                AF[mi][1], BF[ni][1], acc[(S)*4+mi][(NS)*2+ni], 0, 0, 0);                   \
    } } }

#define GLL(gsrc, loff) __builtin_amdgcn_global_load_lds(                                   \
    (const AS1 void*)(gsrc), (AS3 void*)(lds + (loff)), 16, 0, 0)

#define FENCE asm volatile("" ::: "memory")

template<bool HAS_CIN, bool LAST>
__global__ __launch_bounds__(512, 2) void gemm8(
    const unsigned short* __restrict__ A, const unsigned short* __restrict__ W, const int K,
    const float* __restrict__ bsum, const float* __restrict__ Cin,
    float* __restrict__ Hout, float* __restrict__ Cout, const int H)
{
    __shared__ __align__(16) char lds[131072];
    const int t = threadIdx.x;
    const int w = t >> 6, l = t & 63;
    const int wr = w >> 2, wc = w & 3;                 // 2m x 4n wave grid

    // T1: bijective XCD swizzle (nwg always a multiple of 8 here); bx-major
    const int GX = gridDim.x, GY = gridDim.y;
    const int nwg = GX * GY;
    const int bid = (int)blockIdx.y * GX + (int)blockIdx.x;
    const int swz = (bid & 7) * (nwg >> 3) + (bid >> 3);
    const int m0 = (swz / GY) * 256, n0 = (swz % GY) * 256;

    const int colsw = ((l & 7) ^ (l >> 3)) * 8;        // swizzled source col granule
    const size_t k128 = (size_t)128 * K;
    const size_t aoff0 = (size_t)(m0 + w * 16 + (l >> 3)) * K + colsw;
    const size_t aoff1 = aoff0 + (size_t)8 * K;
    const size_t boff0 = (size_t)(n0 + w * 16 + (l >> 3)) * K + colsw;
    const size_t boff1 = boff0 + (size_t)8 * K;
    const int sd0 = w * 2048 + l * 16;                 // LDS byte dest (within region)
    const int sd1 = sd0 + 1024;

    const int lr128 = (l & 15) * 128;
    const int sw0 = (((l >> 4)    ) ^ (l & 7)) * 16;   // swizzled ds_read granules
    const int sw1 = (((l >> 4) + 4) ^ (l & 7)) * 16;

    f32x4 acc[8][4];
#pragma unroll
    for (int i = 0; i < 8; ++i)
#pragma unroll
        for (int j = 0; j < 4; ++j) acc[i][j] = (f32x4){0.f, 0.f, 0.f, 0.f};

    const int NT = K >> 6;   // >= 4 for all levels

    // ---- prologue: tile0 A+B; tile1 B halves (A(1) staged in iter 0)
    GLL(A + aoff0, sd0);                      GLL(A + aoff1, sd1);                 // A(0) h0
    GLL(A + aoff0 + k128, 16384 + sd0);       GLL(A + aoff1 + k128, 16384 + sd1);  // A(0) h1
    GLL(W + boff0, 32768 + sd0);              GLL(W + boff1, 32768 + sd1);         // B(0) h0
    GLL(W + boff0 + k128, 49152 + sd0);       GLL(W + boff1 + k128, 49152 + sd1);  // B(0) h1
    GLL(W + boff0 + 64, 98304 + sd0);         GLL(W + boff1 + 64, 98304 + sd1);    // B(1) h0
    GLL(W + boff0 + k128 + 64, 114688 + sd0); GLL(W + boff1 + k128 + 64, 114688 + sd1); // B(1) h1

    bf16x8 aLo[4][2], aHi[4][2], bF0[2][2], bF1[2][2];

    for (int tt = 0; tt < NT; ++tt) {
        const int q = tt & 1, qn = q ^ 1;
        const int rbA = (q << 16) + (wr << 14) + lr128;
        const int rbB = (q << 16) + 32768 + wc * 8192 + lr128;
        const bool st1 = (tt + 1 < NT), st2 = (tt + 2 < NT);

        // ---- top rendezvous: tile-t halves landed (A(t),B(t)); B(t+1) may fly
        if (st1) { asm volatile("s_waitcnt vmcnt(4)" ::: "memory"); }
        else     { asm volatile("s_waitcnt vmcnt(0)" ::: "memory"); }
        __builtin_amdgcn_s_barrier();
        FENCE;

        // ---- issue ALL reads up front: aLo(8), bF0(4), bF1(4), then aHi(8)
#pragma unroll
        for (int mi = 0; mi < 4; ++mi) {
            aLo[mi][0] = *(const bf16x8*)(lds + rbA + mi * 2048 + sw0);
            aLo[mi][1] = *(const bf16x8*)(lds + rbA + mi * 2048 + sw1);
        }
#pragma unroll
        for (int ni = 0; ni < 2; ++ni) {
            bF0[ni][0] = *(const bf16x8*)(lds + rbB + ni * 2048 + sw0);
            bF0[ni][1] = *(const bf16x8*)(lds + rbB + ni * 2048 + sw1);
            bF1[ni][0] = *(const bf16x8*)(lds + rbB + 4096 + ni * 2048 + sw0);
            bF1[ni][1] = *(const bf16x8*)(lds + rbB + 4096 + ni * 2048 + sw1);
        }
        if (st1) {   // stage A(t+1)->qn (safe: barrier proved tile t-1 reads done)
            const size_t ko1 = (size_t)(tt + 1) * 64;
            GLL(A + aoff0 + ko1, (qn << 16) + sd0);
            GLL(A + aoff1 + ko1, (qn << 16) + sd1);
            GLL(A + aoff0 + k128 + ko1, (qn << 16) + 16384 + sd0);
            GLL(A + aoff1 + k128 + ko1, (qn << 16) + 16384 + sd1);
        }
#pragma unroll
        for (int mi = 0; mi < 4; ++mi) {
            aHi[mi][0] = *(const bf16x8*)(lds + rbA + 8192 + mi * 2048 + sw0);
            aHi[mi][1] = *(const bf16x8*)(lds + rbA + 8192 + mi * 2048 + sw1);
        }

        // ---- cluster 1: MFMAs start when aLo/bF0 land; bF1/aHi still in flight
        __builtin_amdgcn_s_setprio(1);
        QUAD(aLo, 0, 0, bF0);
        QUAD(aLo, 0, 1, bF1);
        __builtin_amdgcn_s_setprio(0);
        __builtin_amdgcn_s_barrier();
        FENCE;

        // ---- cluster 2: stage B(t+2)->q (bF reads done: cluster-1 consumed them
        //      before the barrier); MFMA with aHi (landed under cluster 1)
        if (st2) {
            const size_t ko2 = (size_t)(tt + 2) * 64;
            GLL(W + boff0 + ko2, (q << 16) + 32768 + sd0);
            GLL(W + boff1 + ko2, (q << 16) + 32768 + sd1);
            GLL(W + boff0 + k128 + ko2, (q << 16) + 49152 + sd0);
            GLL(W + boff1 + k128 + ko2, (q << 16) + 49152 + sd1);
        }
        __builtin_amdgcn_s_setprio(1);
        QUAD(aHi, 1, 1, bF1);
        QUAD(aHi, 1, 0, bF0);
        __builtin_amdgcn_s_setprio(0);
    }

    // ---- fused LSTM-cell epilogue: wave's 64-col group = 4 gates x 16 outputs
    const int ocol = (n0 >> 6) * 16 + wc * 16 + (l & 15);
    const int bb = n0 + wc * 64 + (l & 15);
    const float b0 = bsum[bb], b1 = bsum[bb + 16], b2 = bsum[bb + 32], b3 = bsum[bb + 48];
    const int mrow0 = m0 + wr * 128 + (l >> 4) * 4;
#pragma unroll
    for (int mi = 0; mi < 8; ++mi)
#pragma unroll
        for (int j = 0; j < 4; ++j) {
            const size_t m = (size_t)(mrow0 + mi * 16 + j);
            const float gi = acc[mi][0][j] + b0;
            const float gf = acc[mi][1][j] + b1;
            const float gg = acc[mi][2][j] + b2;
            const float go = acc[mi][3][j] + b3;
            float c2 = sigm(gi) * tanh_(gg);
            if (HAS_CIN) c2 += sigm(gf) * Cin[m * H + ocol];
            const float h2 = sigm(go) * tanh_(c2);
            Hout[m * H + ocol] = h2;
            if (!LAST) Cout[m * H + ocol] = c2;
        }
}

// ---------------- conv1d(k=3,pad=1)+softmax for h AND c in one launch
template<int L>
__global__ __launch_bounds__(256) void conv_dual(
    const float* __restrict__ Hin, const float* __restrict__ Cin,
    const float* __restrict__ w3h, const float* __restrict__ w3c,
    unsigned short* __restrict__ Yb, int ldYb, float* __restrict__ cbuf)
{
    __shared__ float xs[L + 2];
    __shared__ float red[8];
    const int nrows = gridDim.x >> 1;
    const bool isC = (int)blockIdx.x >= nrows;
    const int row = isC ? ((int)blockIdx.x - nrows) : (int)blockIdx.x;
    const float* Xs = isC ? Cin : Hin;
    const float* w3 = isC ? w3c : w3h;
    const int t = threadIdx.x;
    const size_t base = (size_t)row * L;
    const float w0 = w3[0], w1 = w3[1], w2 = w3[2];
    if (t == 0) { xs[0] = 0.f; xs[L + 1] = 0.f; }
    for (int i = t; i < L; i += 256) xs[i + 1] = Xs[base + i];
    __syncthreads();
    constexpr int E = L / 256;
    float y[E];
    float vmax = -3.4e38f;
#pragma unroll
    for (int i = 0; i < E; ++i) {
        const int c = t + i * 256;
        y[i] = w0 * xs[c] + w1 * xs[c + 1] + w2 * xs[c + 2];
        vmax = fmaxf(vmax, y[i]);
    }
#pragma unroll
    for (int off = 32; off >= 1; off >>= 1) vmax = fmaxf(vmax, __shfl_xor(vmax, off));
    if ((t & 63) == 0) red[t >> 6] = vmax;
    __syncthreads();
    vmax = fmaxf(fmaxf(red[0], red[1]), fmaxf(red[2], red[3]));
    float s = 0.f;
#pragma unroll
    for (int i = 0; i < E; ++i) { y[i] = __expf(y[i] - vmax); s += y[i]; }
#pragma unroll
    for (int off = 32; off >= 1; off >>= 1) s += __shfl_xor(s, off);
    if ((t & 63) == 0) red[4 + (t >> 6)] = s;
    __syncthreads();
    const float inv = 1.f / (red[4] + red[5] + red[6] + red[7]);
#pragma unroll
    for (int i = 0; i < E; ++i) {
        const int c = t + i * 256;
        const float v = y[i] * inv;
        if (isC) cbuf[base + c] = v;
        else     Yb[(size_t)row * ldYb + c] = f2bf(v);
    }
}

extern "C" void kernel_launch(void* const* d_in, const int* in_sizes, int n_in,
                              void* d_out, int out_size, void* d_ws, size_t ws_size,
                              hipStream_t stream)
{
    (void)in_sizes; (void)n_in; (void)out_size; (void)ws_size;
    const float* spec  = (const float*)d_in[0];
    const float* Wih1  = (const float*)d_in[1];
    const float* Whh1  = (const float*)d_in[2];
    const float* bih1  = (const float*)d_in[3];
    const float* bhh1  = (const float*)d_in[4];
    const float* Wih2  = (const float*)d_in[5];
    const float* Whh2  = (const float*)d_in[6];
    const float* bih2  = (const float*)d_in[7];
    const float* bhh2  = (const float*)d_in[8];
    const float* Wih3  = (const float*)d_in[9];
    const float* Whh3  = (const float*)d_in[10];
    const float* bih3  = (const float*)d_in[11];
    const float* bhh3  = (const float*)d_in[12];
    const float* Wih4  = (const float*)d_in[13];
    const float* bih4  = (const float*)d_in[15];
    const float* bhh4  = (const float*)d_in[16];
    const float* w2_1h = (const float*)d_in[17];
    const float* w2_1c = (const float*)d_in[18];
    const float* w3_2h = (const float*)d_in[19];
    const float* w3_2c = (const float*)d_in[20];
    const float* w4_3h = (const float*)d_in[21];
    const float* w4_3c = (const float*)d_in[22];

    char* ws = (char*)d_ws;
    float*          h   = (float*)(ws + 0);                         // 16 MiB
    float*          c   = (float*)(ws + (size_t)16777216);          // 16 MiB
    float*          cb  = (float*)(ws + (size_t)33554432);          // 16 MiB
    unsigned short* sB  = (unsigned short*)(ws + (size_t)50331648); // 16 MiB (spec bf16, L4 A)
    unsigned short* X   = (unsigned short*)(ws + (size_t)67108864); // 24 MiB (A_cat3 -> A_cat1)
    unsigned short* Y   = (unsigned short*)(ws + (size_t)92274688); // 24 MiB (A_cat2)
    unsigned short* Wc1 = (unsigned short*)(ws + (size_t)117440512);// 24 MiB
    unsigned short* Wc2 = (unsigned short*)(ws + (size_t)142606336);//  6 MiB
    unsigned short* Wc3 = (unsigned short*)(ws + (size_t)148897792);// 1.5 MiB
    unsigned short* W4  = (unsigned short*)(ws + (size_t)150470656);// 0.25 MiB
    float*          bs1 = (float*)(ws + (size_t)150732800);
    float*          bs2 = bs1 + 4096;
    float*          bs3 = bs2 + 4096;
    float*          bs4 = bs3 + 4096;

    // ---- conversions (Whh4 unused: level-4 h_in == 0)
    cvt_spec3<<<2048, 256, 0, stream>>>(spec, sB, X, Y, 2097152);
    PArgs pa;
    pa.s[0] = { Wih1, Wc1,       0, 1024, 9, 3072,    0 };
    pa.s[1] = { Whh1, Wc1, 2097152, 1024, 8, 3072, 2048 };
    pa.s[2] = { Wih2, Wc2, 3145728,  512, 8, 1536,    0 };
    pa.s[3] = { Whh2, Wc2, 3670016,  512, 7, 1536, 1024 };
    pa.s[4] = { Wih3, Wc3, 3932160,  256, 7,  768,    0 };
    pa.s[5] = { Whh3, Wc3, 4063232,  256, 6,  768,  512 };
    pa.s[6] = { Wih4, W4,  4128768,  128, 6,  256,    0 };
    pa.total = 4161536;
    cvt_permW_all<<<2048, 256, 0, stream>>>(pa);
    bias_all<<<30, 256, 0, stream>>>(bih1, bhh1, bih2, bhh2, bih3, bhh3, bih4, bhh4,
                                     bs1, bs2, bs3, bs4);

    // ---- Level 4: M=32768, N=512 (H=128), K=256
    gemm8<false, false><<<dim3(128, 2), 512, 0, stream>>>(sB, W4, 256, bs4, nullptr, h, c, 128);
    conv_dual<256><<<32768, 256, 0, stream>>>(h, c, w4_3h, w4_3c, X + 512, 768, cb);

    // ---- Level 3: M=16384, N=1024 (H=256), K=768
    gemm8<true, false><<<dim3(64, 4), 512, 0, stream>>>(X, Wc3, 768, bs3, cb, h, c, 256);
    cvt_specA<<<2048, 256, 0, stream>>>(spec, X, 2097152);     // A_cat1 spec part (X@768 free)
    conv_dual<512><<<16384, 256, 0, stream>>>(h, c, w3_2h, w3_2c, Y + 1024, 1536, cb);

    // ---- Level 2: M=8192, N=2048 (H=512), K=1536
    gemm8<true, false><<<dim3(32, 8), 512, 0, stream>>>(Y, Wc2, 1536, bs2, cb, h, c, 512);
    conv_dual<1024><<<8192, 256, 0, stream>>>(h, c, w2_1h, w2_1c, X + 2048, 3072, cb);

    // ---- Level 1: M=4096, N=4096 (H=1024), K=3072; h1 -> d_out (f32)
    gemm8<true, true><<<dim3(16, 16), 512, 0, stream>>>(X, Wc1, 3072, bs1, cb, (float*)d_out, nullptr, 1024);
}